// Round 3
// baseline (127.229 us; speedup 1.0000x reference)
//
#include <hip/hip_runtime.h>

#define N 8000
#define SEQ 200
#define MAX_STEPS 199

#define REG_THREADS 256
#define HALF_BLOCKS 1024
#define REG_BLOCKS (2 * HALF_BLOCKS)
#define SIDE_THREADS (HALF_BLOCKS * REG_THREADS)   // 262144 threads per matrix
#define NN4 16000000                               // N*N/4 float4 per matrix
// 61 full strides: 61*262144 = 15,990,784 <= 16,000,000; tail = 9216
#define FULL_STRIDES 61

typedef float f4 __attribute__((ext_vector_type(4)));

__device__ __forceinline__ float log_sum4(f4 v) {
    // log(|x|+1) = ln2 * log2(|x|+1); ln2 factored out at the atomic.
    return __log2f(fabsf(v[0]) + 1.0f) + __log2f(fabsf(v[1]) + 1.0f) +
           __log2f(fabsf(v[2]) + 1.0f) + __log2f(fabsf(v[3]) + 1.0f);
}

// -------------------------------------------------------------------------
// K1: zero out; gather D[t][i] into workspace.
// -------------------------------------------------------------------------
__global__ void k_init_gather(const int* __restrict__ a,
                              const float* __restrict__ s,
                              const float* __restrict__ pe,
                              const float* __restrict__ ne,
                              float* __restrict__ D, int useD,
                              float* __restrict__ out) {
    if (blockIdx.x == 0 && threadIdx.x == 0) out[0] = 0.0f;
    if (!useD) return;

    __shared__ int   sa[MAX_STEPS];
    __shared__ float ss[MAX_STEPS];
    for (int i = threadIdx.x; i < MAX_STEPS; i += blockDim.x) {
        sa[i] = a[i];
        ss[i] = s[i];
    }
    __syncthreads();

    int idx = blockIdx.x * blockDim.x + threadIdx.x;
    const int total = MAX_STEPS * MAX_STEPS;
    if (idx < total) {
        int t = idx / MAX_STEPS;
        int i = idx - t * MAX_STEPS;
        float st = ss[t];
        size_t off = (size_t)sa[t] * N + (size_t)sa[i];
        float d = st * pe[off] + (1.0f - st) * ne[off];
        D[idx] = d;
    }
}

// -------------------------------------------------------------------------
// K2: regularizer. Blocks [0,1024) stream pe with NON-TEMPORAL loads
//     (pure HBM, no LLC allocation); blocks [1024,2048) read ne with
//     cached loads (ne = 256 MB = exactly L3 size -> should go resident).
//     4 loads hoisted per iteration for memory-level parallelism.
// -------------------------------------------------------------------------
__global__ void __launch_bounds__(REG_THREADS)
k_reg(const float* __restrict__ pe,
      const float* __restrict__ ne,
      float* __restrict__ out) {
    const bool is_ne = (blockIdx.x >= HALF_BLOCKS);
    const f4* __restrict__ src = (const f4*)(is_ne ? ne : pe);
    const int tid =
        (blockIdx.x - (is_ne ? HALF_BLOCKS : 0)) * REG_THREADS + threadIdx.x;

    float acc = 0.0f;

    // 15 batches of 4 strides (strides 0..59)
    #pragma unroll 1
    for (int b = 0; b < 15; ++b) {
        size_t base = (size_t)tid + (size_t)(b * 4) * SIDE_THREADS;
        f4 v0, v1, v2, v3;
        if (is_ne) {
            v0 = src[base];
            v1 = src[base + (size_t)SIDE_THREADS];
            v2 = src[base + (size_t)2 * SIDE_THREADS];
            v3 = src[base + (size_t)3 * SIDE_THREADS];
        } else {
            v0 = __builtin_nontemporal_load(&src[base]);
            v1 = __builtin_nontemporal_load(&src[base + (size_t)SIDE_THREADS]);
            v2 = __builtin_nontemporal_load(&src[base + (size_t)2 * SIDE_THREADS]);
            v3 = __builtin_nontemporal_load(&src[base + (size_t)3 * SIDE_THREADS]);
        }
        acc += log_sum4(v0);
        acc += log_sum4(v1);
        acc += log_sum4(v2);
        acc += log_sum4(v3);
    }
    // stride 60 (full)
    {
        size_t p = (size_t)tid + (size_t)60 * SIDE_THREADS;
        f4 v = is_ne ? src[p] : __builtin_nontemporal_load(&src[p]);
        acc += log_sum4(v);
    }
    // stride 61 (guarded tail: only tid < 9216)
    {
        size_t p = (size_t)tid + (size_t)FULL_STRIDES * SIDE_THREADS;
        if (p < (size_t)NN4) {
            f4 v = is_ne ? src[p] : __builtin_nontemporal_load(&src[p]);
            acc += log_sum4(v);
        }
    }

    // wave64 reduce
    #pragma unroll
    for (int o = 32; o > 0; o >>= 1) acc += __shfl_down(acc, o);
    __shared__ float wsum[REG_THREADS / 64];
    int lane = threadIdx.x & 63;
    int wid  = threadIdx.x >> 6;
    if (lane == 0) wsum[wid] = acc;
    __syncthreads();
    if (threadIdx.x == 0) {
        float b = 0.0f;
        #pragma unroll
        for (int w = 0; w < REG_THREADS / 64; ++w) b += wsum[w];
        // 0.5 * ln(2) folded here (log2 -> ln conversion)
        atomicAdd(out, 0.34657359027997264f * b);
    }
}

// -------------------------------------------------------------------------
// K3: sequential loss (unchanged).
// -------------------------------------------------------------------------
__global__ void k_loss(const int* __restrict__ a,
                       const float* __restrict__ s,
                       const float* __restrict__ pe,
                       const float* __restrict__ ne,
                       const float* __restrict__ kp,
                       const float* __restrict__ D, int useD,
                       float* __restrict__ out) {
    __shared__ int   sa[MAX_STEPS];
    __shared__ float ss[MAX_STEPS];
    int tid = threadIdx.x;
    for (int i = tid; i < MAX_STEPS; i += blockDim.x) {
        sa[i] = a[i];
        ss[i] = s[i];
    }
    __syncthreads();

    __shared__ int V;
    if (tid == 0) {
        int v = MAX_STEPS;
        for (int t = 0; t < MAX_STEPS; ++t) {
            if (ss[t] < 0.0f) { v = t; break; }
        }
        V = v;
    }
    __syncthreads();

    float li = 0.0f;
    if (tid < MAX_STEPS && tid < V) {
        int j = sa[tid];
        float k = kp[j];
        if (useD) {
            int t = 0;
            for (; t + 8 <= tid; t += 8) {
                float d[8];
                #pragma unroll
                for (int u = 0; u < 8; ++u) d[u] = D[(t + u) * MAX_STEPS + tid];
                #pragma unroll
                for (int u = 0; u < 8; ++u)
                    k = fminf(fmaxf(k + d[u], -30.0f), 30.0f);
            }
            for (; t < tid; ++t) {
                float d = D[t * MAX_STEPS + tid];
                k = fminf(fmaxf(k + d, -30.0f), 30.0f);
            }
        } else {
            for (int t = 0; t < tid; ++t) {
                float st = ss[t];
                size_t off = (size_t)sa[t] * N + (size_t)j;
                float d = st * pe[off] + (1.0f - st) * ne[off];
                k = fminf(fmaxf(k + d, -30.0f), 30.0f);
            }
        }
        float p = fminf(fmaxf(k, 0.01f), 0.99f);
        li = -(ss[tid] * logf(p) + (1.0f - ss[tid]) * logf(1.0f - p));
    }

    #pragma unroll
    for (int o = 32; o > 0; o >>= 1) li += __shfl_down(li, o);
    __shared__ float wsum[4];
    int lane = tid & 63;
    int wid  = tid >> 6;
    if (lane == 0) wsum[wid] = li;
    __syncthreads();
    if (tid == 0) {
        float total = wsum[0] + wsum[1] + wsum[2] + wsum[3];
        atomicAdd(out, total);
    }
}

extern "C" void kernel_launch(void* const* d_in, const int* in_sizes, int n_in,
                              void* d_out, int out_size, void* d_ws, size_t ws_size,
                              hipStream_t stream) {
    const int*   a  = (const int*)d_in[0];
    const float* s  = (const float*)d_in[1];
    const float* pe = (const float*)d_in[2];
    const float* ne = (const float*)d_in[3];
    const float* kp = (const float*)d_in[4];
    float* out = (float*)d_out;

    float* D = (float*)d_ws;
    int useD = (ws_size >= sizeof(float) * MAX_STEPS * MAX_STEPS) ? 1 : 0;

    const int gatherBlocks = (MAX_STEPS * MAX_STEPS + 255) / 256;
    k_init_gather<<<gatherBlocks, 256, 0, stream>>>(a, s, pe, ne, D, useD, out);
    k_reg<<<REG_BLOCKS, REG_THREADS, 0, stream>>>(pe, ne, out);
    k_loss<<<1, 256, 0, stream>>>(a, s, pe, ne, kp, D, useD, out);
}